// Round 15
// baseline (97.005 us; speedup 1.0000x reference)
//
#include <hip/hip_runtime.h>
#include <hip/hip_bf16.h>
#include <math.h>
#include <stdint.h>

#define DM 4096
#define NEXP 64
#define TOKW 32            // tokens per block
#define NSTEP 32           // K steps of 128
#define NTOK 16384

typedef short bf16x8 __attribute__((ext_vector_type(8)));
typedef float f32x4  __attribute__((ext_vector_type(4)));

// RN split: x = hi + lo + f, |f| <= 2^-18 |x|. lo = x - hi is Sterbenz-exact.
__device__ __forceinline__ void split2(float f0, float f1, uint32_t& hw, uint32_t& lw) {
    float2 ff; ff.x = f0; ff.y = f1;
    __hip_bfloat162 h = __float22bfloat162_rn(ff);
    union { __hip_bfloat162 b; uint32_t u; } ch; ch.b = h;
    hw = ch.u;
    float h0 = __bfloat162float(h.x);
    float h1 = __bfloat162float(h.y);
    float2 gg; gg.x = f0 - h0; gg.y = f1 - h1;
    __hip_bfloat162 l = __float22bfloat162_rn(gg);
    union { __hip_bfloat162 b; uint32_t u; } cl; cl.b = l;
    lw = cl.u;
}

// ---------------- pre-pass: W fp32 -> RN bf16 hi/lo, fragment-ordered blob ----------------
// BK=32 layout: byte = c*8192 + n4*1024 + ln*16 (hi; +4096 lo)
// where ln = (e&15) | (kgran<<4), kgran = 0..3 (8 bf16 each), n4 = e>>4.
__global__ __launch_bounds__(256) void wsplit_kernel(const float* __restrict__ W,
                                                     char* __restrict__ blob) {
    const int c   = blockIdx.x;        // 0..127
    const int tid = threadIdx.x;       // 0..255
    const int e   = tid >> 2;          // expert 0..63
    const int g   = tid & 3;           // k-granule 0..3 (8 bf16 each)

    const float* src = W + (size_t)e * DM + c * 32 + g * 8;
    float x[8];
    *(float4*)(x)     = *(const float4*)(src);
    *(float4*)(x + 4) = *(const float4*)(src + 4);

    uint32_t hiw[4], low[4];
#pragma unroll
    for (int j = 0; j < 4; ++j) split2(x[2 * j], x[2 * j + 1], hiw[j], low[j]);

    const int ln = (e & 15) | (g << 4);
    const int n4 = e >> 4;
    const size_t base = (size_t)c * 8192 + (size_t)n4 * 1024 + (size_t)ln * 16;
    *(uint4*)(blob + base)        = *(uint4*)hiw;   // hi plane
    *(uint4*)(blob + base + 4096) = *(uint4*)low;   // lo plane
}

// ---------------- main kernel ----------------
// 512 thr = 8 waves = (m,n) tiles (2 x 4). Full K per accumulator (acc = 4
// VGPR). Per 128-k step the block cooperatively stages X[32 rows][512 B]
// into a 2-buffer LDS ring: each global_load_lds covers 2 rows x 512 B
// CONTIGUOUS (DRAM page-friendly), src lane-permuted for an XOR bank
// swizzle, dst linear. Counted vmcnt keeps next-step staging in flight
// across raw barriers (never drains to 0 mid-loop). B streams from the
// L2-resident blob. 3-product split GEMM: hh + hl + lh.
__global__ __launch_bounds__(512, 4) void router_mfma_kernel(
    const float* __restrict__ X,
    const char* __restrict__ blob,
    const float* __restrict__ Bv,
    float* __restrict__ out)
{
    __shared__ __align__(16) char smem[32768];   // 2 bufs x [32 rows][512 B]; logits overlay after loop

    const int tid  = threadIdx.x;      // 0..511
    const int lane = tid & 63;
    const int wv   = tid >> 6;         // 0..7
    const int mw   = wv >> 2;          // token half  (m)
    const int nw   = wv & 3;           // expert quad (n)
    const long tok0 = (long)blockIdx.x * TOKW;

    const int tk = lane & 15;          // row-in-16 / expert col
    const int kg = lane >> 4;          // k-granule within 32-k chunk
    const int sw = tk & 7;             // ds_read swizzle key

    // stage step s into buf b: 2 instrs/wave, each 1 KB = rows (wv*4+j*2, +1) x 512 B.
    // LDS unit (r, u) holds X[r][s*128 + (u ^ (r&7))*4 ..+4] -> XOR-swizzled, src
    // is a within-row lane permutation so coalescing (and DRAM bursts) stay linear.
    auto stage = [&](int s, int b) {
#pragma unroll
        for (int j = 0; j < 2; ++j) {
            const int r  = wv * 4 + j * 2 + (lane >> 5);
            const int us = (lane & 31) ^ (r & 7);
            const float* src = X + (size_t)(tok0 + r) * DM + s * 128 + us * 4;
            char* dst = smem + b * 16384 + (wv * 4 + j * 2) * 512 + lane * 16;
            __builtin_amdgcn_global_load_lds(
                (const __attribute__((address_space(1))) void*)src,
                (__attribute__((address_space(3))) void*)dst, 16, 0, 0);
        }
    };

    f32x4 acc = (f32x4)0.0f;

    stage(0, 0);                       // prologue (no drain: first in-loop wait handles it)

#pragma unroll 1
    for (int s = 0; s < NSTEP; ++s) {
        const int b = s & 1;

        // ---- B loads for this step's 4 chunks (L2; oldest after prev-stage) ----
        bf16x8 bh[4], bl[4];
        const char* bb0 = blob + (size_t)(4 * s) * 8192 + (size_t)nw * 1024 + (size_t)lane * 16;
#pragma unroll
        for (int ks = 0; ks < 4; ++ks) {
            bh[ks] = *(const bf16x8*)(bb0 + ks * 8192);
            bl[ks] = *(const bf16x8*)(bb0 + ks * 8192 + 4096);
        }

        // ---- issue next-step staging (stays in flight through this step) ----
        if (s + 1 < NSTEP) stage(s + 1, b ^ 1);

        // ---- retire own prev-stage (oldest 2), leave B + next-stage flying ----
        if (s + 1 < NSTEP) { asm volatile("s_waitcnt vmcnt(10)" ::: "memory"); }
        else               { asm volatile("s_waitcnt vmcnt(8)"  ::: "memory"); }
        __builtin_amdgcn_sched_barrier(0);
        __builtin_amdgcn_s_barrier();   // all waves' stage(b) retired -> buf b readable

        // ---- A fragments from LDS (swizzled), split, MFMA ----
        const char* rb = smem + b * 16384 + (mw * 16 + tk) * 512;
#pragma unroll
        for (int ks = 0; ks < 4; ++ks) {
            const int v = ks * 8 + kg * 2;
            f32x4 r0 = *(const f32x4*)(rb + ((v       ^ sw) * 16));
            f32x4 r1 = *(const f32x4*)(rb + (((v + 1) ^ sw) * 16));
            uint32_t hw[4], lw[4];
            split2(r0.x, r0.y, hw[0], lw[0]);
            split2(r0.z, r0.w, hw[1], lw[1]);
            split2(r1.x, r1.y, hw[2], lw[2]);
            split2(r1.z, r1.w, hw[3], lw[3]);
            bf16x8 ah = *(bf16x8*)hw;
            bf16x8 al = *(bf16x8*)lw;
            acc = __builtin_amdgcn_mfma_f32_16x16x32_bf16(ah, bh[ks], acc, 0, 0, 0);
            acc = __builtin_amdgcn_mfma_f32_16x16x32_bf16(ah, bl[ks], acc, 0, 0, 0);
            acc = __builtin_amdgcn_mfma_f32_16x16x32_bf16(al, bh[ks], acc, 0, 0, 0);
        }

        __builtin_amdgcn_s_barrier();   // all reads of buf b done -> next step may overwrite it
    }

    // ---- logits overlay (token = mw*16 + kg*4 + r, expert = nw*16 + tk) ----
    float* pf = (float*)smem;
#pragma unroll
    for (int r = 0; r < 4; ++r)
        pf[(mw * 16 + kg * 4 + r) * 64 + nw * 16 + tk] = acc[r];
    __syncthreads();

    // ---- epilogue: bias + softmax + top-2 + dense scatter (lane = expert) ----
    const float bias = Bv[lane];
#pragma unroll 1
    for (int j = 0; j < 4; ++j) {
        const int t = wv * 4 + j;
        float v = pf[t * 64 + lane] + bias;

        float m1 = v;        int i1 = lane;
        float m2 = -3.4e38f; int i2 = 127;
#pragma unroll
        for (int s2 = 1; s2 < 64; s2 <<= 1) {
            float om1 = __shfl_xor(m1, s2, 64);
            int   oi1 = __shfl_xor(i1, s2, 64);
            float om2 = __shfl_xor(m2, s2, 64);
            int   oi2 = __shfl_xor(i2, s2, 64);
            bool bw2 = (om1 > m1) || (om1 == m1 && oi1 < i1);
            float l1v = bw2 ? m1 : om1;  int l1i = bw2 ? i1 : oi1;
            float w2v = bw2 ? om2 : m2;  int w2i = bw2 ? oi2 : i2;
            if (bw2) { m1 = om1; i1 = oi1; }
            bool tw = (l1v > w2v) || (l1v == w2v && l1i < w2i);
            m2 = tw ? l1v : w2v;  i2 = tw ? l1i : w2i;
        }

        float p = expf(v - m1);
        float ssum = p;
#pragma unroll
        for (int s2 = 1; s2 < 64; s2 <<= 1) ssum += __shfl_xor(ssum, s2, 64);

        float sc = (lane == i1 || lane == i2) ? (p / ssum) : 0.0f;
        out[(size_t)(tok0 + t) * NEXP + lane] = sc;
    }
}

extern "C" void kernel_launch(void* const* d_in, const int* in_sizes, int n_in,
                              void* d_out, int out_size, void* d_ws, size_t ws_size,
                              hipStream_t stream) {
    const float* X  = (const float*)d_in[0];   // [4,4096,4096] fp32
    const float* W  = (const float*)d_in[1];   // [64,4096] fp32
    const float* Bv = (const float*)d_in[2];   // [64] fp32
    float* out = (float*)d_out;                // [4,4096,64] fp32

    // W split blob: 128 chunks * 8 KiB = 1 MiB in d_ws
    char* blob = (char*)d_ws;
    wsplit_kernel<<<dim3(128), dim3(256), 0, stream>>>(W, blob);

    router_mfma_kernel<<<dim3(NTOK / TOKW), dim3(512), 0, stream>>>(X, blob, Bv, out);
}

// Round 17
// 91.187 us; speedup vs baseline: 1.0638x; 1.0638x over previous
//
#include <hip/hip_runtime.h>
#include <hip/hip_bf16.h>
#include <math.h>
#include <stdint.h>

#define DM 4096
#define NEXP 64
#define BK 64              // k per chunk
#define NCH (DM / BK)      // 64 chunks
#define TOKW 32            // tokens per block
#define KSPLIT 8           // waves per block, each owns NCH/KSPLIT chunks
#define CHPS (NCH / KSPLIT)

typedef short bf16x8 __attribute__((ext_vector_type(8)));
typedef float f32x4  __attribute__((ext_vector_type(4)));

// RN split: x = hi + lo + f, |f| <= 2^-18 |x|. lo = x - hi is Sterbenz-exact.
__device__ __forceinline__ void split2(float f0, float f1, uint32_t& hw, uint32_t& lw) {
    float2 ff; ff.x = f0; ff.y = f1;
    __hip_bfloat162 h = __float22bfloat162_rn(ff);
    union { __hip_bfloat162 b; uint32_t u; } ch; ch.b = h;
    hw = ch.u;
    float h0 = __bfloat162float(h.x);
    float h1 = __bfloat162float(h.y);
    float2 gg; gg.x = f0 - h0; gg.y = f1 - h1;
    __hip_bfloat162 l = __float22bfloat162_rn(gg);
    union { __hip_bfloat162 b; uint32_t u; } cl; cl.b = l;
    lw = cl.u;
}

// ---------------- pre-pass: W fp32 -> RN bf16 hi/lo, fragment-ordered blob ----------------
// blob byte layout: c*16384 + ks*4096 + n4*1024 + lane*16 (hi; +8192 for lo)
// where lane = (e&15) | ((kgran&3)<<4), n4 = e>>4, ks = kgran>>2.
// 256 blocks (64 chunks x 4 expert-quarters) so the pre-pass spreads across CUs.
__global__ __launch_bounds__(128) void wsplit_kernel(const float* __restrict__ W,
                                                     char* __restrict__ blob) {
    const int c   = blockIdx.x;        // 0..63
    const int eq  = blockIdx.y;        // 0..3
    const int tid = threadIdx.x;       // 0..127
    const int e   = eq * 16 + (tid >> 3);  // expert 0..63
    const int g   = tid & 7;           // k-granule 0..7 (8 bf16 each)

    const float* src = W + (size_t)e * DM + c * BK + g * 8;
    float x[8];
    *(float4*)(x)     = *(const float4*)(src);
    *(float4*)(x + 4) = *(const float4*)(src + 4);

    uint32_t hiw[4], low[4];
#pragma unroll
    for (int j = 0; j < 4; ++j) split2(x[2 * j], x[2 * j + 1], hiw[j], low[j]);

    const int ks = g >> 2;
    const int ln = (e & 15) | ((g & 3) << 4);
    const int n4 = e >> 4;
    const size_t base = (size_t)c * 16384 + (size_t)ks * 4096 + (size_t)n4 * 1024 + (size_t)ln * 16;
    *(uint4*)(blob + base)        = *(uint4*)hiw;   // hi plane
    *(uint4*)(blob + base + 8192) = *(uint4*)low;   // lo plane
}

// ---------------- main kernel ----------------
// 512 threads = 8 waves, no barriers in the K-loop. Wave w owns K-chunks
// [w*CHPS,(w+1)*CHPS) for the block's 32 tokens. A (=X) fragments load
// per-lane direct from global with NON-TEMPORAL loads (X is read-once and
// would otherwise thrash L2, evicting the B-blob); B fragments stream from
// the now-L2-resident blob. 3-product split GEMM: hh + hl + lh.
__global__ __launch_bounds__(512, 4) void router_mfma_kernel(
    const float* __restrict__ X,
    const char* __restrict__ blob,
    const float* __restrict__ Bv,
    float* __restrict__ out)
{
    __shared__ float part[KSPLIT][TOKW][NEXP];   // 64 KiB

    const int tid  = threadIdx.x;      // 0..511
    const int lane = tid & 63;
    const int wv   = tid >> 6;         // 0..7 = K-slice
    const long tok0 = (long)blockIdx.x * TOKW;

    const int tk = lane & 15;          // token-within-16 / expert col
    const int kg = lane >> 4;          // k-granule within 32-k subtile

    // per-lane A row bases (floats), at this wave's K-slice origin
    const float* a0 = X + (size_t)(tok0 + tk) * DM + (size_t)wv * (CHPS * BK) + kg * 8;
    const float* a1 = a0 + (size_t)16 * DM;
    const char*  bw = blob + (size_t)(wv * CHPS) * 16384;

    f32x4 acc[2][4];
#pragma unroll
    for (int m = 0; m < 2; ++m)
#pragma unroll
        for (int n = 0; n < 4; ++n) acc[m][n] = (f32x4)0.0f;

#pragma unroll 1
    for (int ci = 0; ci < CHPS; ++ci) {
        const char* bb = bw + (size_t)ci * 16384;

        // ---- A: 8 floats per (m, ks), per-lane, non-temporal (bypass L2) ----
        f32x4 ar[2][2][2];   // [m][ks][2 x f32x4]
#pragma unroll
        for (int m = 0; m < 2; ++m) {
            const float* am = (m == 0) ? a0 : a1;
#pragma unroll
            for (int ks = 0; ks < 2; ++ks) {
                const f32x4* p4 = (const f32x4*)(am + ci * BK + ks * 32);
                ar[m][ks][0] = __builtin_nontemporal_load(p4);
                ar[m][ks][1] = __builtin_nontemporal_load(p4 + 1);
            }
        }

        // split to fragments
        bf16x8 ah[2][2], al[2][2];   // [ks][m]
#pragma unroll
        for (int m = 0; m < 2; ++m)
#pragma unroll
            for (int ks = 0; ks < 2; ++ks) {
                uint32_t hw[4], lw[4];
                split2(ar[m][ks][0].x, ar[m][ks][0].y, hw[0], lw[0]);
                split2(ar[m][ks][0].z, ar[m][ks][0].w, hw[1], lw[1]);
                split2(ar[m][ks][1].x, ar[m][ks][1].y, hw[2], lw[2]);
                split2(ar[m][ks][1].z, ar[m][ks][1].w, hw[3], lw[3]);
                ah[ks][m] = *(bf16x8*)hw;
                al[ks][m] = *(bf16x8*)lw;
            }

        // ---- B from L2 (fragment-ordered blob) + MFMA (3 products) ----
#pragma unroll
        for (int ks = 0; ks < 2; ++ks) {
#pragma unroll
            for (int n = 0; n < 4; ++n) {
                const size_t bo = (size_t)ks * 4096 + (size_t)n * 1024 + (size_t)lane * 16;
                bf16x8 bh = *(const bf16x8*)(bb + bo);
                bf16x8 bl = *(const bf16x8*)(bb + 8192 + bo);
#pragma unroll
                for (int m = 0; m < 2; ++m) {
                    acc[m][n] = __builtin_amdgcn_mfma_f32_16x16x32_bf16(ah[ks][m], bh, acc[m][n], 0, 0, 0);
                    acc[m][n] = __builtin_amdgcn_mfma_f32_16x16x32_bf16(ah[ks][m], bl, acc[m][n], 0, 0, 0);
                    acc[m][n] = __builtin_amdgcn_mfma_f32_16x16x32_bf16(al[ks][m], bh, acc[m][n], 0, 0, 0);
                }
            }
        }
    }

    // ---- write per-slice partial logits: token = m*16 + kg*4 + r, expert = n*16 + tk ----
#pragma unroll
    for (int m = 0; m < 2; ++m)
#pragma unroll
        for (int n = 0; n < 4; ++n)
#pragma unroll
            for (int r = 0; r < 4; ++r)
                part[wv][m * 16 + kg * 4 + r][n * 16 + tk] = acc[m][n][r];
    __syncthreads();

    // ---- reduce over K-slices: 2048 cells, 4 per thread ----
#pragma unroll
    for (int i = 0; i < 4; ++i) {
        const int cell = tid + i * 512;
        const int t = cell >> 6;
        const int e = cell & 63;
        float s = part[0][t][e];
#pragma unroll
        for (int w = 1; w < KSPLIT; ++w) s += part[w][t][e];
        part[0][t][e] = s;
    }
    __syncthreads();

    // ---- epilogue: bias + softmax + top-2 + dense scatter (lane = expert) ----
    const float bias = Bv[lane];
#pragma unroll 1
    for (int j = 0; j < TOKW / KSPLIT; ++j) {
        const int t = wv * (TOKW / KSPLIT) + j;
        float v = part[0][t][lane] + bias;

        float m1 = v;        int i1 = lane;
        float m2 = -3.4e38f; int i2 = 127;
#pragma unroll
        for (int s = 1; s < 64; s <<= 1) {
            float om1 = __shfl_xor(m1, s, 64);
            int   oi1 = __shfl_xor(i1, s, 64);
            float om2 = __shfl_xor(m2, s, 64);
            int   oi2 = __shfl_xor(i2, s, 64);
            bool bw2 = (om1 > m1) || (om1 == m1 && oi1 < i1);
            float l1v = bw2 ? m1 : om1;  int l1i = bw2 ? i1 : oi1;
            float w2v = bw2 ? om2 : m2;  int w2i = bw2 ? oi2 : i2;
            if (bw2) { m1 = om1; i1 = oi1; }
            bool tw = (l1v > w2v) || (l1v == w2v && l1i < w2i);
            m2 = tw ? l1v : w2v;  i2 = tw ? l1i : w2i;
        }

        float p = expf(v - m1);
        float ssum = p;
#pragma unroll
        for (int s = 1; s < 64; s <<= 1) ssum += __shfl_xor(ssum, s, 64);

        float sc = (lane == i1 || lane == i2) ? (p / ssum) : 0.0f;
        out[(size_t)(tok0 + t) * NEXP + lane] = sc;
    }
}

extern "C" void kernel_launch(void* const* d_in, const int* in_sizes, int n_in,
                              void* d_out, int out_size, void* d_ws, size_t ws_size,
                              hipStream_t stream) {
    const float* X  = (const float*)d_in[0];   // [4,4096,4096] fp32
    const float* W  = (const float*)d_in[1];   // [64,4096] fp32
    const float* Bv = (const float*)d_in[2];   // [64] fp32
    float* out = (float*)d_out;                // [4,4096,64] fp32

    // W split blob: 64 chunks * 16 KiB = 1 MiB in d_ws
    char* blob = (char*)d_ws;
    wsplit_kernel<<<dim3(NCH, 4), dim3(128), 0, stream>>>(W, blob);

    const int n_tokens = 4 * 4096;             // 16384
    router_mfma_kernel<<<dim3(n_tokens / TOKW), dim3(512), 0, stream>>>(X, blob, Bv, out);
}

// Round 18
// 74.760 us; speedup vs baseline: 1.2976x; 1.2197x over previous
//
#include <hip/hip_runtime.h>
#include <hip/hip_bf16.h>
#include <math.h>
#include <stdint.h>

#define DM 4096
#define NEXP 64
#define BK 64              // k per chunk
#define NCH (DM / BK)      // 64 chunks
#define TOKW 32            // tokens per block
#define KSPLIT 8           // waves per block, each owns NCH/KSPLIT chunks
#define CHPS (NCH / KSPLIT)

typedef short bf16x8 __attribute__((ext_vector_type(8)));
typedef float f32x4  __attribute__((ext_vector_type(4)));

// RN split: x = hi + lo + f, |f| <= 2^-18 |x|. lo = x - hi is Sterbenz-exact.
__device__ __forceinline__ void split2(float f0, float f1, uint32_t& hw, uint32_t& lw) {
    float2 ff; ff.x = f0; ff.y = f1;
    __hip_bfloat162 h = __float22bfloat162_rn(ff);
    union { __hip_bfloat162 b; uint32_t u; } ch; ch.b = h;
    hw = ch.u;
    float h0 = __bfloat162float(h.x);
    float h1 = __bfloat162float(h.y);
    float2 gg; gg.x = f0 - h0; gg.y = f1 - h1;
    __hip_bfloat162 l = __float22bfloat162_rn(gg);
    union { __hip_bfloat162 b; uint32_t u; } cl; cl.b = l;
    lw = cl.u;
}

// ---------------- pre-pass: W fp32 -> RN bf16 hi/lo, fragment-ordered blob ----------------
// blob byte layout: c*16384 + ks*4096 + n4*1024 + lane*16 (hi; +8192 for lo)
// where lane = (e&15) | ((kgran&3)<<4), n4 = e>>4, ks = kgran>>2.
// 256 blocks (64 chunks x 4 expert-quarters) so the pre-pass spreads across CUs.
__global__ __launch_bounds__(128) void wsplit_kernel(const float* __restrict__ W,
                                                     char* __restrict__ blob) {
    const int c   = blockIdx.x;        // 0..63
    const int eq  = blockIdx.y;        // 0..3
    const int tid = threadIdx.x;       // 0..127
    const int e   = eq * 16 + (tid >> 3);  // expert 0..63
    const int g   = tid & 7;           // k-granule 0..7 (8 bf16 each)

    const float* src = W + (size_t)e * DM + c * BK + g * 8;
    float x[8];
    *(float4*)(x)     = *(const float4*)(src);
    *(float4*)(x + 4) = *(const float4*)(src + 4);

    uint32_t hiw[4], low[4];
#pragma unroll
    for (int j = 0; j < 4; ++j) split2(x[2 * j], x[2 * j + 1], hiw[j], low[j]);

    const int ks = g >> 2;
    const int ln = (e & 15) | ((g & 3) << 4);
    const int n4 = e >> 4;
    const size_t base = (size_t)c * 16384 + (size_t)ks * 4096 + (size_t)n4 * 1024 + (size_t)ln * 16;
    *(uint4*)(blob + base)        = *(uint4*)hiw;   // hi plane
    *(uint4*)(blob + base + 8192) = *(uint4*)low;   // lo plane
}

// ---------------- main kernel ----------------
// 512 threads = 8 waves, no barriers in the K-loop. Wave w owns K-chunks
// [w*CHPS,(w+1)*CHPS) for the block's 32 tokens. A (=X) fragments load
// per-lane direct from global; B fragments stream from the L2-resident blob.
// 3-product split GEMM: hh + hl + lh (ll term ~3e-6 logit error, dropped).
__global__ __launch_bounds__(512, 4) void router_mfma_kernel(
    const float* __restrict__ X,
    const char* __restrict__ blob,
    const float* __restrict__ Bv,
    float* __restrict__ out)
{
    __shared__ float part[KSPLIT][TOKW][NEXP];   // 64 KiB

    const int tid  = threadIdx.x;      // 0..511
    const int lane = tid & 63;
    const int wv   = tid >> 6;         // 0..7 = K-slice
    const long tok0 = (long)blockIdx.x * TOKW;

    const int tk = lane & 15;          // token-within-16 / expert col
    const int kg = lane >> 4;          // k-granule within 32-k subtile

    // per-lane A row bases (floats), at this wave's K-slice origin
    const float* a0 = X + (size_t)(tok0 + tk) * DM + (size_t)wv * (CHPS * BK) + kg * 8;
    const float* a1 = a0 + (size_t)16 * DM;
    const char*  bw = blob + (size_t)(wv * CHPS) * 16384;

    f32x4 acc[2][4];
#pragma unroll
    for (int m = 0; m < 2; ++m)
#pragma unroll
        for (int n = 0; n < 4; ++n) acc[m][n] = (f32x4)0.0f;

#pragma unroll 1
    for (int ci = 0; ci < CHPS; ++ci) {
        const char* bb = bw + (size_t)ci * 16384;

        // ---- A: 8 floats per (m, ks), per-lane direct from global ----
        float ar[2][2][8];   // [m][ks][8]
#pragma unroll
        for (int m = 0; m < 2; ++m) {
            const float* am = (m == 0) ? a0 : a1;
#pragma unroll
            for (int ks = 0; ks < 2; ++ks) {
                const float* p = am + ci * BK + ks * 32;
                *(float4*)(ar[m][ks])     = *(const float4*)(p);
                *(float4*)(ar[m][ks] + 4) = *(const float4*)(p + 4);
            }
        }

        // split to fragments
        bf16x8 ah[2][2], al[2][2];   // [ks][m]
#pragma unroll
        for (int m = 0; m < 2; ++m)
#pragma unroll
            for (int ks = 0; ks < 2; ++ks) {
                uint32_t hw[4], lw[4];
#pragma unroll
                for (int j = 0; j < 4; ++j)
                    split2(ar[m][ks][2 * j], ar[m][ks][2 * j + 1], hw[j], lw[j]);
                ah[ks][m] = *(bf16x8*)hw;
                al[ks][m] = *(bf16x8*)lw;
            }

        // ---- B from L2 (fragment-ordered blob) + MFMA (3 products) ----
#pragma unroll
        for (int ks = 0; ks < 2; ++ks) {
#pragma unroll
            for (int n = 0; n < 4; ++n) {
                const size_t bo = (size_t)ks * 4096 + (size_t)n * 1024 + (size_t)lane * 16;
                bf16x8 bh = *(const bf16x8*)(bb + bo);
                bf16x8 bl = *(const bf16x8*)(bb + 8192 + bo);
#pragma unroll
                for (int m = 0; m < 2; ++m) {
                    acc[m][n] = __builtin_amdgcn_mfma_f32_16x16x32_bf16(ah[ks][m], bh, acc[m][n], 0, 0, 0);
                    acc[m][n] = __builtin_amdgcn_mfma_f32_16x16x32_bf16(ah[ks][m], bl, acc[m][n], 0, 0, 0);
                    acc[m][n] = __builtin_amdgcn_mfma_f32_16x16x32_bf16(al[ks][m], bh, acc[m][n], 0, 0, 0);
                }
            }
        }
    }

    // ---- write per-slice partial logits: token = m*16 + kg*4 + r, expert = n*16 + tk ----
#pragma unroll
    for (int m = 0; m < 2; ++m)
#pragma unroll
        for (int n = 0; n < 4; ++n)
#pragma unroll
            for (int r = 0; r < 4; ++r)
                part[wv][m * 16 + kg * 4 + r][n * 16 + tk] = acc[m][n][r];
    __syncthreads();

    // ---- reduce over K-slices: 2048 cells, 4 per thread ----
#pragma unroll
    for (int i = 0; i < 4; ++i) {
        const int cell = tid + i * 512;
        const int t = cell >> 6;
        const int e = cell & 63;
        float s = part[0][t][e];
#pragma unroll
        for (int w = 1; w < KSPLIT; ++w) s += part[w][t][e];
        part[0][t][e] = s;
    }
    __syncthreads();

    // ---- epilogue: bias + softmax + top-2 + dense scatter (lane = expert) ----
    const float bias = Bv[lane];
#pragma unroll 1
    for (int j = 0; j < TOKW / KSPLIT; ++j) {
        const int t = wv * (TOKW / KSPLIT) + j;
        float v = part[0][t][lane] + bias;

        float m1 = v;        int i1 = lane;
        float m2 = -3.4e38f; int i2 = 127;
#pragma unroll
        for (int s = 1; s < 64; s <<= 1) {
            float om1 = __shfl_xor(m1, s, 64);
            int   oi1 = __shfl_xor(i1, s, 64);
            float om2 = __shfl_xor(m2, s, 64);
            int   oi2 = __shfl_xor(i2, s, 64);
            bool bw2 = (om1 > m1) || (om1 == m1 && oi1 < i1);
            float l1v = bw2 ? m1 : om1;  int l1i = bw2 ? i1 : oi1;
            float w2v = bw2 ? om2 : m2;  int w2i = bw2 ? oi2 : i2;
            if (bw2) { m1 = om1; i1 = oi1; }
            bool tw = (l1v > w2v) || (l1v == w2v && l1i < w2i);
            m2 = tw ? l1v : w2v;  i2 = tw ? l1i : w2i;
        }

        float p = expf(v - m1);
        float ssum = p;
#pragma unroll
        for (int s = 1; s < 64; s <<= 1) ssum += __shfl_xor(ssum, s, 64);

        float sc = (lane == i1 || lane == i2) ? (p / ssum) : 0.0f;
        out[(size_t)(tok0 + t) * NEXP + lane] = sc;
    }
}

extern "C" void kernel_launch(void* const* d_in, const int* in_sizes, int n_in,
                              void* d_out, int out_size, void* d_ws, size_t ws_size,
                              hipStream_t stream) {
    const float* X  = (const float*)d_in[0];   // [4,4096,4096] fp32
    const float* W  = (const float*)d_in[1];   // [64,4096] fp32
    const float* Bv = (const float*)d_in[2];   // [64] fp32
    float* out = (float*)d_out;                // [4,4096,64] fp32

    // W split blob: 64 chunks * 16 KiB = 1 MiB in d_ws
    char* blob = (char*)d_ws;
    wsplit_kernel<<<dim3(NCH, 4), dim3(128), 0, stream>>>(W, blob);

    const int n_tokens = 4 * 4096;             // 16384
    router_mfma_kernel<<<dim3(n_tokens / TOKW), dim3(512), 0, stream>>>(X, blob, Bv, out);
}